// Round 6
// baseline (1331.280 us; speedup 1.0000x reference)
//
#include <hip/hip_runtime.h>

#define BSZ 16
#define SQ  512
#define DM  256
#define NHD 4
#define NLY 6
#define NND 8192      // nodes = BSZ*SQ
#define NEG 131072    // edges
#define DHD 64

typedef float  f32x4  __attribute__((ext_vector_type(4)));
typedef __bf16 bf16x8 __attribute__((ext_vector_type(8)));

#define N_SRC 31
struct SrcPtrs { const void* p[N_SRC]; };

__device__ __host__ __forceinline__ long asz_at(int i) {
    const int asz[N_SRC] = {16384, 131072, 1, 2, 2, 128, 64, 8192, 128, 1, 128, 128,
                            32768, 256, 65536, 256, 131072, 1179648, 4608, 393216, 1536,
                            1536, 1536, 1536, 1536, 786432, 3072, 786432, 1536, 256, 256};
    return asz[i];
}

// Canonicalize every float input to bf16 (detect f32 vs bf16 via ln1_w == ones).
__global__ void convert_arena(SrcPtrs sp, __bf16* __restrict__ arena, long total) {
    long gid = (long)blockIdx.x * 256 + threadIdx.x;
    if (gid >= total) return;
    bool isbf = (*(const unsigned int*)sp.p[21]) == 0x3F803F80u;
    long off = 0;
    #pragma unroll
    for (int i = 0; i < N_SRC; i++) {
        long sz = asz_at(i), pad = (sz + 15) & ~15L;
        if (gid >= off && gid < off + sz) {
            long k = gid - off;
            float v = isbf ? (float)((const __bf16*)sp.p[i])[k]
                           : ((const float*)sp.p[i])[k];
            arena[gid] = (__bf16)v;
        }
        off += pad;
    }
}

// Diagnostic: write a constant everywhere (f32 now).
__global__ void diag_write(float* __restrict__ out, int n, float val) {
    int i = blockIdx.x * 256 + threadIdx.x;
    if (i < n) out[i] = val;
}

// ---------------------------------------------------------------- GINE 1
__global__ void gine1_edge(const __bf16* __restrict__ x, const __bf16* __restrict__ ea,
                           const int* __restrict__ src, const int* __restrict__ dst,
                           const __bf16* __restrict__ ew, const __bf16* __restrict__ eb,
                           float* __restrict__ agg) {
    int e = blockIdx.x * 256 + threadIdx.x;
    if (e >= NEG) return;
    float a = (float)ea[e];
    int s = src[e], d = dst[e];
    float m0 = (float)x[s * 2 + 0] + a * (float)ew[0] + (float)eb[0];
    float m1 = (float)x[s * 2 + 1] + a * (float)ew[1] + (float)eb[1];
    if (m0 > 0.f) atomicAdd(&agg[d * 2 + 0], m0);
    if (m1 > 0.f) atomicAdd(&agg[d * 2 + 1], m1);
}

__global__ void gine1_node(const __bf16* __restrict__ x, const float* __restrict__ agg,
                           const __bf16* __restrict__ eps,
                           const __bf16* __restrict__ w1, const __bf16* __restrict__ b1,
                           const __bf16* __restrict__ w2, const __bf16* __restrict__ b2,
                           float* __restrict__ h1f) {
    __shared__ float hid[2][64];
    int hl = threadIdx.x >> 7, c = threadIdx.x & 127;
    int n = blockIdx.x * 2 + hl;
    float e1 = 1.f + (float)eps[0];
    float z0 = e1 * (float)x[n * 2 + 0] + agg[n * 2 + 0];
    float z1 = e1 * (float)x[n * 2 + 1] + agg[n * 2 + 1];
    if (c < 64) {
        float h = z0 * (float)w1[c * 2 + 0] + z1 * (float)w1[c * 2 + 1] + (float)b1[c];
        hid[hl][c] = h > 0.f ? h : 0.f;
    }
    __syncthreads();
    float s = (float)b2[c];
    #pragma unroll
    for (int h = 0; h < 64; h++) s += hid[hl][h] * (float)w2[c * 64 + h];
    h1f[(long)n * 128 + c] = s > 0.f ? s : 0.f;   // outer relu from _forward
}

// ---------------------------------------------------------------- GINE 2
__global__ void gine2_edge(const float* __restrict__ h1f, const __bf16* __restrict__ ea,
                           const int* __restrict__ src, const int* __restrict__ dst,
                           const __bf16* __restrict__ ew, const __bf16* __restrict__ eb,
                           float* __restrict__ agg) {
    long gid = (long)blockIdx.x * 256 + threadIdx.x;
    int e = (int)(gid >> 7), c = (int)(gid & 127);
    float m = h1f[(long)src[e] * 128 + c] + (float)ea[e] * (float)ew[c] + (float)eb[c];
    if (m > 0.f) atomicAdd(&agg[(long)dst[e] * 128 + c], m);
}

__global__ void make_z2(const float* __restrict__ h1f, const float* __restrict__ agg,
                        const __bf16* __restrict__ eps, __bf16* __restrict__ z2b) {
    long gid = (long)blockIdx.x * 256 + threadIdx.x;
    float e1 = 1.f + (float)eps[0];
    z2b[gid] = (__bf16)(e1 * h1f[gid] + agg[gid]);
}

// ---------------------------------------------------------------- attention drop-mask (bit=1 -> bias 1.0, else 2.0)
__global__ void drop_mask(const int* __restrict__ src, const int* __restrict__ dst,
                          const int* __restrict__ drop, unsigned int* __restrict__ mask) {
    int e = blockIdx.x * 256 + threadIdx.x;
    if (e >= NEG) return;
    if (drop[e]) {
        int s = src[e], d = dst[e];
        int b = s >> 9, ls = s & 511, ld = d & 511;
        atomicOr(&mask[((long)(b * 512 + ls)) * 16 + (ld >> 5)], 1u << (ld & 31));
        atomicOr(&mask[((long)(b * 512 + ld)) * 16 + (ls >> 5)], 1u << (ls & 31));
    }
}

// ---------------------------------------------------------------- LayerNorm (row=256) -> bf16
__global__ __launch_bounds__(256) void ln_k(const float* __restrict__ xin,
                                            const __bf16* __restrict__ w,
                                            const __bf16* __restrict__ b,
                                            __bf16* __restrict__ out) {
    int lane = threadIdx.x & 63;
    int row = blockIdx.x * 4 + (threadIdx.x >> 6);
    const float* xr = xin + (long)row * 256;
    f32x4 v = *(const f32x4*)(xr + lane * 4);
    float s  = v[0] + v[1] + v[2] + v[3];
    float s2 = v[0]*v[0] + v[1]*v[1] + v[2]*v[2] + v[3]*v[3];
    #pragma unroll
    for (int o = 32; o > 0; o >>= 1) { s += __shfl_xor(s, o); s2 += __shfl_xor(s2, o); }
    float mean = s * (1.f / 256.f);
    float var  = s2 * (1.f / 256.f) - mean * mean;
    float rstd = rsqrtf(var + 1e-5f);
    __attribute__((aligned(8))) __bf16 o4[4];
    #pragma unroll
    for (int k = 0; k < 4; k++)
        o4[k] = (__bf16)((v[k] - mean) * rstd * (float)w[lane * 4 + k] + (float)b[lane * 4 + k]);
    *(unsigned long long*)(out + (long)row * 256 + lane * 4) = *(const unsigned long long*)o4;
}

// ---------------------------------------------------------------- final LayerNorm -> FLOAT32 output
__global__ __launch_bounds__(256) void ln_out(const float* __restrict__ xin,
                                              const __bf16* __restrict__ w,
                                              const __bf16* __restrict__ b,
                                              float* __restrict__ out) {
    int lane = threadIdx.x & 63;
    int row = blockIdx.x * 4 + (threadIdx.x >> 6);
    const float* xr = xin + (long)row * 256;
    f32x4 v = *(const f32x4*)(xr + lane * 4);
    float s  = v[0] + v[1] + v[2] + v[3];
    float s2 = v[0]*v[0] + v[1]*v[1] + v[2]*v[2] + v[3]*v[3];
    #pragma unroll
    for (int o = 32; o > 0; o >>= 1) { s += __shfl_xor(s, o); s2 += __shfl_xor(s2, o); }
    float mean = s * (1.f / 256.f);
    float var  = s2 * (1.f / 256.f) - mean * mean;
    float rstd = rsqrtf(var + 1e-5f);
    f32x4 o4;
    #pragma unroll
    for (int k = 0; k < 4; k++)
        o4[k] = (v[k] - mean) * rstd * (float)w[lane * 4 + k] + (float)b[lane * 4 + k];
    *(f32x4*)(out + (long)row * 256 + lane * 4) = o4;
}

// ---------------------------------------------------------------- MFMA GEMM  C = A @ W^T (+bias, act, resid/pos, qkv)
__device__ __forceinline__ void gload_lds16(const void* g, void* l) {
    __builtin_amdgcn_global_load_lds(
        (const __attribute__((address_space(1))) void*)g,
        (__attribute__((address_space(3))) void*)l, 16, 0, 0);
}

__global__ __launch_bounds__(256) void gemm_bt(
        const __bf16* __restrict__ A, const __bf16* __restrict__ W,
        const __bf16* __restrict__ bias, __bf16* __restrict__ outb,
        float* __restrict__ outf, const float* __restrict__ resid,
        const __bf16* __restrict__ pos, __bf16* __restrict__ vT,
        int K, int ldout, int act, int qkvmode) {
    __shared__ __attribute__((aligned(16))) __bf16 lA[128 * 32];
    __shared__ __attribute__((aligned(16))) __bf16 lB[128 * 32];
    const int tid = threadIdx.x, lane = tid & 63, w = tid >> 6;
    const int wm = w & 1, wn = w >> 1;
    const int quad = lane >> 4, l16 = lane & 15;
    const long tm = (long)blockIdx.x * 128, tn = (long)blockIdx.y * 128;
    f32x4 acc[4][4] = {};
    for (int k0 = 0; k0 < K; k0 += 32) {
        __syncthreads();
        #pragma unroll
        for (int ch = w; ch < 8; ch += 4) {
            int lin = ch * 1024 + lane * 16;
            int row = lin >> 6;
            int kb  = lin & 63;
            gload_lds16((const char*)A + ((tm + row) * K + k0) * 2 + kb, (char*)lA + lin);
            gload_lds16((const char*)W + ((tn + row) * K + k0) * 2 + kb, (char*)lB + lin);
        }
        __syncthreads();
        const int kg = quad * 8;
        bf16x8 af[4], bfv[4];
        #pragma unroll
        for (int i = 0; i < 4; i++) af[i]  = *(const bf16x8*)&lA[(wm * 64 + i * 16 + l16) * 32 + kg];
        #pragma unroll
        for (int j = 0; j < 4; j++) bfv[j] = *(const bf16x8*)&lB[(wn * 64 + j * 16 + l16) * 32 + kg];
        #pragma unroll
        for (int i = 0; i < 4; i++)
            #pragma unroll
            for (int j = 0; j < 4; j++)
                acc[i][j] = __builtin_amdgcn_mfma_f32_16x16x32_bf16(af[i], bfv[j], acc[i][j], 0, 0, 0);
    }
    #pragma unroll
    for (int i = 0; i < 4; i++) {
        #pragma unroll
        for (int j = 0; j < 4; j++) {
            #pragma unroll
            for (int r = 0; r < 4; r++) {
                int m = (int)tm + wm * 64 + i * 16 + quad * 4 + r;
                int n = (int)tn + wn * 64 + j * 16 + l16;
                float v = acc[i][j][r];
                if (bias) v += (float)bias[n];
                if (act == 1) v = v > 0.f ? v : 0.f;
                else if (act == 2) v = v / (1.f + __expf(-v));
                if (qkvmode) {
                    if (n < 512) {
                        if (n < 256) v *= 0.125f;           // fold 1/sqrt(DH)=1/8 into q (exact)
                        outb[(long)m * ldout + n] = (__bf16)v;
                    } else {
                        int vc = n - 512, hh = vc >> 6, d = vc & 63;
                        int b = m >> 9, sdx = m & 511;
                        vT[(((long)(b * NHD + hh) * DHD + d) << 9) + sdx] = (__bf16)v;
                    }
                } else if (outf) {
                    if (resid) v += resid[(long)m * ldout + n];
                    if (pos)   v += (float)pos[(long)(m & 511) * ldout + n];
                    outf[(long)m * ldout + n] = v;
                } else {
                    outb[(long)m * ldout + n] = (__bf16)v;
                }
            }
        }
    }
}

// ---------------------------------------------------------------- fused attention: QK^T + mask-bias + softmax + P@V
__global__ __launch_bounds__(256) void attn_fused(const __bf16* __restrict__ qk,
                                                  const __bf16* __restrict__ vT,
                                                  const unsigned int* __restrict__ mask,
                                                  __bf16* __restrict__ attno) {
    __shared__ __bf16 pt[4][16 * 512];   // 64 KB
    const int lane = threadIdx.x & 63, w = threadIdx.x >> 6;
    const int qb = blockIdx.x, h = blockIdx.y, b = blockIdx.z;
    const int qr0 = qb * 64 + w * 16;
    const int quad = lane >> 4, l16 = lane & 15;
    const int bh = b * NHD + h;
    const __bf16* qbase = qk + ((long)(b * 512 + qr0 + l16)) * 512 + h * 64 + quad * 8;
    bf16x8 qf0 = *(const bf16x8*)(qbase);
    bf16x8 qf1 = *(const bf16x8*)(qbase + 32);
    f32x4 acc[32];
    #pragma unroll
    for (int t = 0; t < 32; t++) {
        const __bf16* kbase = qk + ((long)(b * 512 + t * 16 + l16)) * 512 + 256 + h * 64 + quad * 8;
        bf16x8 kf0 = *(const bf16x8*)(kbase);
        bf16x8 kf1 = *(const bf16x8*)(kbase + 32);
        f32x4 z = {0.f, 0.f, 0.f, 0.f};
        z = __builtin_amdgcn_mfma_f32_16x16x32_bf16(qf0, kf0, z, 0, 0, 0);
        acc[t] = __builtin_amdgcn_mfma_f32_16x16x32_bf16(qf1, kf1, z, 0, 0, 0);
    }
    const unsigned int* mrow = mask + ((long)(b * 512 + qr0 + quad * 4)) * 16;
    float mx[4] = {-1e30f, -1e30f, -1e30f, -1e30f};
    #pragma unroll
    for (int t = 0; t < 32; t++)
        #pragma unroll
        for (int r = 0; r < 4; r++) {
            unsigned int wd = mrow[r * 16 + (t >> 1)];
            float bias = 2.f - (float)((wd >> (((t & 1) << 4) + l16)) & 1u);
            float v = acc[t][r] + bias;
            acc[t][r] = v;
            mx[r] = fmaxf(mx[r], v);
        }
    #pragma unroll
    for (int r = 0; r < 4; r++)
        #pragma unroll
        for (int o = 1; o < 16; o <<= 1) mx[r] = fmaxf(mx[r], __shfl_xor(mx[r], o));
    float sm[4] = {0.f, 0.f, 0.f, 0.f};
    #pragma unroll
    for (int t = 0; t < 32; t++)
        #pragma unroll
        for (int r = 0; r < 4; r++) {
            float e = __expf(acc[t][r] - mx[r]);
            acc[t][r] = e;
            sm[r] += e;
        }
    #pragma unroll
    for (int r = 0; r < 4; r++)
        #pragma unroll
        for (int o = 1; o < 16; o <<= 1) sm[r] += __shfl_xor(sm[r], o);
    float inv[4];
    #pragma unroll
    for (int r = 0; r < 4; r++) inv[r] = 1.f / sm[r];
    #pragma unroll
    for (int t = 0; t < 32; t++)
        #pragma unroll
        for (int r = 0; r < 4; r++)
            pt[w][(quad * 4 + r) * 512 + t * 16 + l16] = (__bf16)(acc[t][r] * inv[r]);
    __syncthreads();
    f32x4 oacc[4] = {};
    for (int kk = 0; kk < 512; kk += 32) {
        bf16x8 pf = *(const bf16x8*)&pt[w][l16 * 512 + kk + quad * 8];
        #pragma unroll
        for (int j = 0; j < 4; j++) {
            const __bf16* vrow = vT + ((long)bh * 64 + j * 16 + l16) * 512 + kk + quad * 8;
            bf16x8 vf = *(const bf16x8*)(vrow);
            oacc[j] = __builtin_amdgcn_mfma_f32_16x16x32_bf16(pf, vf, oacc[j], 0, 0, 0);
        }
    }
    #pragma unroll
    for (int j = 0; j < 4; j++)
        #pragma unroll
        for (int r = 0; r < 4; r++) {
            int m = qr0 + quad * 4 + r, d = j * 16 + l16;
            attno[((long)(b * 512 + m)) * 256 + h * 64 + d] = (__bf16)oacc[j][r];
        }
}

// ---------------------------------------------------------------- launch
extern "C" void kernel_launch(void* const* d_in, const int* in_sizes, int n_in,
                              void* d_out, int out_size, void* d_ws, size_t ws_size,
                              hipStream_t stream) {
    const long MB = 1024 * 1024;

    const int exp_sizes[34] = {16384, 131072, 1, 2, 2, 128, 64, 8192, 128, 1, 128, 128,
                               32768, 256, 65536, 256, 131072, 1179648, 4608, 393216, 1536,
                               1536, 1536, 1536, 1536, 786432, 3072, 786432, 1536, 256, 256,
                               262144, 17, 131072};
    int bad = -1;
    if (n_in != 34) bad = 40;
    else for (int i = 0; i < 34; i++) if (in_sizes[i] != exp_sizes[i]) { bad = i; break; }
    if (bad >= 0) {
        diag_write<<<(out_size + 255) / 256, 256, 0, stream>>>((float*)d_out, out_size,
                                                               2048.f + 32.f * bad);
        return;
    }
    if (ws_size < (size_t)(59 * MB)) {
        diag_write<<<(out_size + 255) / 256, 256, 0, stream>>>((float*)d_out, out_size,
                                                               4096.f + 32.f * (float)(ws_size >> 20));
        return;
    }

    const int* ei   = (const int*)d_in[31];
    const int* drop = (const int*)d_in[33];
    const int* esrc = ei;
    const int* edst = ei + NEG;

    // ---- workspace layout (59 MB, no overlays; validated in-bounds in R5) ----
    char* ws = (char*)d_ws;
    float*  xb    = (float*)(ws + 0);                          // 8 MB
    __bf16* arena = (__bf16*)(ws + 8 * MB);                    // 7.1 MB
    unsigned int* maskw = (unsigned int*)(ws + 15 * MB + 512 * 1024); // 0.5 MB
    float*  agg1  = (float*)(ws + 16 * MB);                    // 64 KB
    float*  agg2  = (float*)(ws + 17 * MB);                    // 4 MB
    float*  h1f   = (float*)(ws + 21 * MB);                    // 4 MB
    __bf16* z2b   = (__bf16*)(ws + 25 * MB);                   // 2 MB
    __bf16* t1b   = (__bf16*)(ws + 27 * MB);                   // 4 MB
    __bf16* hnb   = (__bf16*)(ws + 31 * MB);                   // 4 MB
    __bf16* qkb   = (__bf16*)(ws + 35 * MB);                   // 8 MB
    __bf16* vT    = (__bf16*)(ws + 43 * MB);                   // 4 MB
    __bf16* attno = (__bf16*)(ws + 47 * MB);                   // 4 MB
    __bf16* ff1b  = (__bf16*)(ws + 51 * MB);                   // 8 MB

    SrcPtrs sp;
    __bf16* ap[N_SRC];
    long off = 0;
    for (int i = 0; i < N_SRC; i++) {
        sp.p[i] = d_in[i];
        ap[i] = arena + off;
        off += (asz_at(i) + 15) & ~15L;
    }
    convert_arena<<<(int)((off + 255) / 256), 256, 0, stream>>>(sp, arena, off);

    const __bf16 *xA = ap[0], *eaA = ap[1], *eps1A = ap[2], *ew1A = ap[3], *eb1A = ap[4],
                 *n1w1A = ap[5], *n1b1A = ap[6], *n1w2A = ap[7], *n1b2A = ap[8],
                 *eps2A = ap[9], *ew2A = ap[10], *eb2A = ap[11],
                 *n2w1A = ap[12], *n2b1A = ap[13], *n2w2A = ap[14], *n2b2A = ap[15],
                 *posA = ap[16], *ipwA = ap[17], *ipbA = ap[18], *opwA = ap[19], *opbA = ap[20],
                 *ln1wA = ap[21], *ln1bA = ap[22], *ln2wA = ap[23], *ln2bA = ap[24],
                 *f1wA = ap[25], *f1bA = ap[26], *f2wA = ap[27], *f2bA = ap[28],
                 *fnwA = ap[29], *fnbA = ap[30];

    hipMemsetAsync(agg1, 0, (size_t)NND * 2 * 4, stream);
    hipMemsetAsync(agg2, 0, (size_t)NND * 128 * 4, stream);
    hipMemsetAsync(maskw, 0, (size_t)512 * 1024, stream);

    gine1_edge<<<NEG / 256, 256, 0, stream>>>(xA, eaA, esrc, edst, ew1A, eb1A, agg1);
    gine1_node<<<NND / 2, 256, 0, stream>>>(xA, agg1, eps1A, n1w1A, n1b1A, n1w2A, n1b2A, h1f);
    gine2_edge<<<(NEG * 128) / 256, 256, 0, stream>>>(h1f, eaA, esrc, edst, ew2A, eb2A, agg2);
    make_z2<<<(NND * 128) / 256, 256, 0, stream>>>(h1f, agg2, eps2A, z2b);

    gemm_bt<<<dim3(NND / 128, 2), 256, 0, stream>>>(z2b, n2w1A, n2b1A, t1b, nullptr, nullptr, nullptr, nullptr,
                                                    128, 256, 1, 0);
    gemm_bt<<<dim3(NND / 128, 2), 256, 0, stream>>>(t1b, n2w2A, n2b2A, nullptr, xb, nullptr, posA, nullptr,
                                                    256, 256, 0, 0);

    drop_mask<<<NEG / 256, 256, 0, stream>>>(esrc, edst, drop, maskw);

    for (int l = 0; l < NLY; l++) {
        ln_k<<<NND / 4, 256, 0, stream>>>(xb, ln1wA + l * 256, ln1bA + l * 256, hnb);
        gemm_bt<<<dim3(NND / 128, 6), 256, 0, stream>>>(hnb, ipwA + (long)l * 768 * 256, ipbA + l * 768,
                                                        qkb, nullptr, nullptr, nullptr, vT,
                                                        256, 512, 0, 1);
        attn_fused<<<dim3(8, NHD, BSZ), 256, 0, stream>>>(qkb, vT, maskw, attno);
        gemm_bt<<<dim3(NND / 128, 2), 256, 0, stream>>>(attno, opwA + (long)l * 256 * 256, opbA + l * 256,
                                                        nullptr, xb, xb, nullptr, nullptr,
                                                        256, 256, 0, 0);
        ln_k<<<NND / 4, 256, 0, stream>>>(xb, ln2wA + l * 256, ln2bA + l * 256, hnb);
        gemm_bt<<<dim3(NND / 128, 4), 256, 0, stream>>>(hnb, f1wA + (long)l * 512 * 256, f1bA + l * 512,
                                                        ff1b, nullptr, nullptr, nullptr, nullptr,
                                                        256, 512, 2, 0);
        gemm_bt<<<dim3(NND / 128, 2), 256, 0, stream>>>(ff1b, f2wA + (long)l * 256 * 512, f2bA + l * 256,
                                                        nullptr, xb, xb, nullptr, nullptr,
                                                        512, 256, 0, 0);
    }
    ln_out<<<NND / 4, 256, 0, stream>>>(xb, fnwA, fnbA, (float*)d_out);
}

// Round 7
// 1045.733 us; speedup vs baseline: 1.2731x; 1.2731x over previous
//
#include <hip/hip_runtime.h>

#define BSZ 16
#define SQ  512
#define DM  256
#define NHD 4
#define NLY 6
#define NND 8192      // nodes = BSZ*SQ
#define NEG 131072    // edges
#define DHD 64

typedef float  f32x4  __attribute__((ext_vector_type(4)));
typedef __bf16 bf16x8 __attribute__((ext_vector_type(8)));

#define N_SRC 31
struct SrcPtrs { const void* p[N_SRC]; };

__device__ __host__ __forceinline__ long asz_at(int i) {
    const int asz[N_SRC] = {16384, 131072, 1, 2, 2, 128, 64, 8192, 128, 1, 128, 128,
                            32768, 256, 65536, 256, 131072, 1179648, 4608, 393216, 1536,
                            1536, 1536, 1536, 1536, 786432, 3072, 786432, 1536, 256, 256};
    return asz[i];
}

// Canonicalize every float input to bf16 (detect f32 vs bf16 via ln1_w == ones).
__global__ void convert_arena(SrcPtrs sp, __bf16* __restrict__ arena, long total) {
    long gid = (long)blockIdx.x * 256 + threadIdx.x;
    if (gid >= total) return;
    bool isbf = (*(const unsigned int*)sp.p[21]) == 0x3F803F80u;
    long off = 0;
    #pragma unroll
    for (int i = 0; i < N_SRC; i++) {
        long sz = asz_at(i), pad = (sz + 15) & ~15L;
        if (gid >= off && gid < off + sz) {
            long k = gid - off;
            float v = isbf ? (float)((const __bf16*)sp.p[i])[k]
                           : ((const float*)sp.p[i])[k];
            arena[gid] = (__bf16)v;
        }
        off += pad;
    }
}

// ---------------------------------------------------------------- GINE 1
__global__ void gine1_edge(const __bf16* __restrict__ x, const __bf16* __restrict__ ea,
                           const int* __restrict__ src, const int* __restrict__ dst,
                           const __bf16* __restrict__ ew, const __bf16* __restrict__ eb,
                           float* __restrict__ agg) {
    int e = blockIdx.x * 256 + threadIdx.x;
    if (e >= NEG) return;
    float a = (float)ea[e];
    int s = src[e], d = dst[e];
    float m0 = (float)x[s * 2 + 0] + a * (float)ew[0] + (float)eb[0];
    float m1 = (float)x[s * 2 + 1] + a * (float)ew[1] + (float)eb[1];
    if (m0 > 0.f) atomicAdd(&agg[d * 2 + 0], m0);
    if (m1 > 0.f) atomicAdd(&agg[d * 2 + 1], m1);
}

__global__ void gine1_node(const __bf16* __restrict__ x, const float* __restrict__ agg,
                           const __bf16* __restrict__ eps,
                           const __bf16* __restrict__ w1, const __bf16* __restrict__ b1,
                           const __bf16* __restrict__ w2, const __bf16* __restrict__ b2,
                           float* __restrict__ h1f) {
    __shared__ float hid[2][64];
    int hl = threadIdx.x >> 7, c = threadIdx.x & 127;
    int n = blockIdx.x * 2 + hl;
    float e1 = 1.f + (float)eps[0];
    float z0 = e1 * (float)x[n * 2 + 0] + agg[n * 2 + 0];
    float z1 = e1 * (float)x[n * 2 + 1] + agg[n * 2 + 1];
    if (c < 64) {
        float h = z0 * (float)w1[c * 2 + 0] + z1 * (float)w1[c * 2 + 1] + (float)b1[c];
        hid[hl][c] = h > 0.f ? h : 0.f;
    }
    __syncthreads();
    float s = (float)b2[c];
    #pragma unroll
    for (int h = 0; h < 64; h++) s += hid[hl][h] * (float)w2[c * 64 + h];
    h1f[(long)n * 128 + c] = s > 0.f ? s : 0.f;   // outer relu from _forward
}

// ---------------------------------------------------------------- GINE 2
__global__ void gine2_edge(const float* __restrict__ h1f, const __bf16* __restrict__ ea,
                           const int* __restrict__ src, const int* __restrict__ dst,
                           const __bf16* __restrict__ ew, const __bf16* __restrict__ eb,
                           float* __restrict__ agg) {
    long gid = (long)blockIdx.x * 256 + threadIdx.x;
    int e = (int)(gid >> 7), c = (int)(gid & 127);
    float m = h1f[(long)src[e] * 128 + c] + (float)ea[e] * (float)ew[c] + (float)eb[c];
    if (m > 0.f) atomicAdd(&agg[(long)dst[e] * 128 + c], m);
}

__global__ void make_z2(const float* __restrict__ h1f, const float* __restrict__ agg,
                        const __bf16* __restrict__ eps, __bf16* __restrict__ z2b) {
    long gid = (long)blockIdx.x * 256 + threadIdx.x;
    float e1 = 1.f + (float)eps[0];
    z2b[gid] = (__bf16)(e1 * h1f[gid] + agg[gid]);
}

// ---------------------------------------------------------------- attention drop-mask (bit=1 -> bias 1.0, else 2.0)
__global__ void drop_mask(const int* __restrict__ src, const int* __restrict__ dst,
                          const int* __restrict__ drop, unsigned int* __restrict__ mask) {
    int e = blockIdx.x * 256 + threadIdx.x;
    if (e >= NEG) return;
    if (drop[e]) {
        int s = src[e], d = dst[e];
        int b = s >> 9, ls = s & 511, ld = d & 511;
        atomicOr(&mask[((long)(b * 512 + ls)) * 16 + (ld >> 5)], 1u << (ld & 31));
        atomicOr(&mask[((long)(b * 512 + ld)) * 16 + (ls >> 5)], 1u << (ls & 31));
    }
}

// ---------------------------------------------------------------- LayerNorm (row=256) -> bf16
__global__ __launch_bounds__(256) void ln_k(const float* __restrict__ xin,
                                            const __bf16* __restrict__ w,
                                            const __bf16* __restrict__ b,
                                            __bf16* __restrict__ out) {
    int lane = threadIdx.x & 63;
    int row = blockIdx.x * 4 + (threadIdx.x >> 6);
    const float* xr = xin + (long)row * 256;
    f32x4 v = *(const f32x4*)(xr + lane * 4);
    float s  = v[0] + v[1] + v[2] + v[3];
    float s2 = v[0]*v[0] + v[1]*v[1] + v[2]*v[2] + v[3]*v[3];
    #pragma unroll
    for (int o = 32; o > 0; o >>= 1) { s += __shfl_xor(s, o); s2 += __shfl_xor(s2, o); }
    float mean = s * (1.f / 256.f);
    float var  = s2 * (1.f / 256.f) - mean * mean;
    float rstd = rsqrtf(var + 1e-5f);
    __attribute__((aligned(8))) __bf16 o4[4];
    #pragma unroll
    for (int k = 0; k < 4; k++)
        o4[k] = (__bf16)((v[k] - mean) * rstd * (float)w[lane * 4 + k] + (float)b[lane * 4 + k]);
    *(unsigned long long*)(out + (long)row * 256 + lane * 4) = *(const unsigned long long*)o4;
}

// ---------------------------------------------------------------- final LayerNorm -> FLOAT32 output
__global__ __launch_bounds__(256) void ln_out(const float* __restrict__ xin,
                                              const __bf16* __restrict__ w,
                                              const __bf16* __restrict__ b,
                                              float* __restrict__ out) {
    int lane = threadIdx.x & 63;
    int row = blockIdx.x * 4 + (threadIdx.x >> 6);
    const float* xr = xin + (long)row * 256;
    f32x4 v = *(const f32x4*)(xr + lane * 4);
    float s  = v[0] + v[1] + v[2] + v[3];
    float s2 = v[0]*v[0] + v[1]*v[1] + v[2]*v[2] + v[3]*v[3];
    #pragma unroll
    for (int o = 32; o > 0; o >>= 1) { s += __shfl_xor(s, o); s2 += __shfl_xor(s2, o); }
    float mean = s * (1.f / 256.f);
    float var  = s2 * (1.f / 256.f) - mean * mean;
    float rstd = rsqrtf(var + 1e-5f);
    f32x4 o4;
    #pragma unroll
    for (int k = 0; k < 4; k++)
        o4[k] = (v[k] - mean) * rstd * (float)w[lane * 4 + k] + (float)b[lane * 4 + k];
    *(f32x4*)(out + (long)row * 256 + lane * 4) = o4;
}

// ---------------------------------------------------------------- MFMA GEMM  C = A @ W^T, tile 128x64
// Re-tiled from 128x128: grid.y doubles (256..768 blocks) to fix the 1.3% occupancy
// seen in R6 profile (N is only 256..768 on this model). LDS 12 KB, ~90 VGPR.
__device__ __forceinline__ void gload_lds16(const void* g, void* l) {
    __builtin_amdgcn_global_load_lds(
        (const __attribute__((address_space(1))) void*)g,
        (__attribute__((address_space(3))) void*)l, 16, 0, 0);
}

__global__ __launch_bounds__(256) void gemm_bt(
        const __bf16* __restrict__ A, const __bf16* __restrict__ W,
        const __bf16* __restrict__ bias, __bf16* __restrict__ outb,
        float* __restrict__ outf, const float* __restrict__ resid,
        const __bf16* __restrict__ pos, __bf16* __restrict__ vT,
        int K, int ldout, int act, int qkvmode) {
    __shared__ __attribute__((aligned(16))) __bf16 lA[128 * 32];   // 8 KB
    __shared__ __attribute__((aligned(16))) __bf16 lB[64 * 32];    // 4 KB
    const int tid = threadIdx.x, lane = tid & 63, w = tid >> 6;
    const int wm = w & 1, wn = w >> 1;        // wave: 64 rows x 32 cols
    const int quad = lane >> 4, l16 = lane & 15;
    const long tm = (long)blockIdx.x * 128, tn = (long)blockIdx.y * 64;
    f32x4 acc[4][2] = {};
    for (int k0 = 0; k0 < K; k0 += 32) {
        __syncthreads();
        {   // 12 x 1 KB chunks: wave w stages A{w, w+4}, B{w}
            int linA0 = w * 1024 + lane * 16;
            gload_lds16((const char*)A + ((tm + (linA0 >> 6)) * K + k0) * 2 + (linA0 & 63),
                        (char*)lA + linA0);
            int linA1 = (w + 4) * 1024 + lane * 16;
            gload_lds16((const char*)A + ((tm + (linA1 >> 6)) * K + k0) * 2 + (linA1 & 63),
                        (char*)lA + linA1);
            int linB = w * 1024 + lane * 16;
            gload_lds16((const char*)W + ((tn + (linB >> 6)) * K + k0) * 2 + (linB & 63),
                        (char*)lB + linB);
        }
        __syncthreads();
        const int kg = quad * 8;
        bf16x8 af[4], bfv[2];
        #pragma unroll
        for (int i = 0; i < 4; i++) af[i]  = *(const bf16x8*)&lA[(wm * 64 + i * 16 + l16) * 32 + kg];
        #pragma unroll
        for (int j = 0; j < 2; j++) bfv[j] = *(const bf16x8*)&lB[(wn * 32 + j * 16 + l16) * 32 + kg];
        #pragma unroll
        for (int i = 0; i < 4; i++)
            #pragma unroll
            for (int j = 0; j < 2; j++)
                acc[i][j] = __builtin_amdgcn_mfma_f32_16x16x32_bf16(af[i], bfv[j], acc[i][j], 0, 0, 0);
    }
    #pragma unroll
    for (int i = 0; i < 4; i++) {
        #pragma unroll
        for (int j = 0; j < 2; j++) {
            #pragma unroll
            for (int r = 0; r < 4; r++) {
                int m = (int)tm + wm * 64 + i * 16 + quad * 4 + r;
                int n = (int)tn + wn * 32 + j * 16 + l16;
                float v = acc[i][j][r];
                if (bias) v += (float)bias[n];
                if (act == 1) v = v > 0.f ? v : 0.f;
                else if (act == 2) v = v / (1.f + __expf(-v));
                if (qkvmode) {
                    if (n < 512) {
                        if (n < 256) v *= 0.125f;           // fold 1/sqrt(DH)=1/8 into q (exact)
                        outb[(long)m * ldout + n] = (__bf16)v;
                    } else {
                        int vc = n - 512, hh = vc >> 6, d = vc & 63;
                        int b = m >> 9, sdx = m & 511;
                        vT[(((long)(b * NHD + hh) * DHD + d) << 9) + sdx] = (__bf16)v;
                    }
                } else if (outf) {
                    if (resid) v += resid[(long)m * ldout + n];
                    if (pos)   v += (float)pos[(long)(m & 511) * ldout + n];
                    outf[(long)m * ldout + n] = v;
                } else {
                    outb[(long)m * ldout + n] = (__bf16)v;
                }
            }
        }
    }
}

// ---------------------------------------------------------------- fused attention: QK^T + mask-bias + softmax + P@V
__global__ __launch_bounds__(256) void attn_fused(const __bf16* __restrict__ qk,
                                                  const __bf16* __restrict__ vT,
                                                  const unsigned int* __restrict__ mask,
                                                  __bf16* __restrict__ attno) {
    __shared__ __bf16 pt[4][16 * 512];   // 64 KB
    const int lane = threadIdx.x & 63, w = threadIdx.x >> 6;
    const int qb = blockIdx.x, h = blockIdx.y, b = blockIdx.z;
    const int qr0 = qb * 64 + w * 16;
    const int quad = lane >> 4, l16 = lane & 15;
    const int bh = b * NHD + h;
    const __bf16* qbase = qk + ((long)(b * 512 + qr0 + l16)) * 512 + h * 64 + quad * 8;
    bf16x8 qf0 = *(const bf16x8*)(qbase);
    bf16x8 qf1 = *(const bf16x8*)(qbase + 32);
    f32x4 acc[32];
    #pragma unroll
    for (int t = 0; t < 32; t++) {
        const __bf16* kbase = qk + ((long)(b * 512 + t * 16 + l16)) * 512 + 256 + h * 64 + quad * 8;
        bf16x8 kf0 = *(const bf16x8*)(kbase);
        bf16x8 kf1 = *(const bf16x8*)(kbase + 32);
        f32x4 z = {0.f, 0.f, 0.f, 0.f};
        z = __builtin_amdgcn_mfma_f32_16x16x32_bf16(qf0, kf0, z, 0, 0, 0);
        acc[t] = __builtin_amdgcn_mfma_f32_16x16x32_bf16(qf1, kf1, z, 0, 0, 0);
    }
    const unsigned int* mrow = mask + ((long)(b * 512 + qr0 + quad * 4)) * 16;
    float mx[4] = {-1e30f, -1e30f, -1e30f, -1e30f};
    #pragma unroll
    for (int t = 0; t < 32; t++)
        #pragma unroll
        for (int r = 0; r < 4; r++) {
            unsigned int wd = mrow[r * 16 + (t >> 1)];
            float bias = 2.f - (float)((wd >> (((t & 1) << 4) + l16)) & 1u);
            float v = acc[t][r] + bias;
            acc[t][r] = v;
            mx[r] = fmaxf(mx[r], v);
        }
    #pragma unroll
    for (int r = 0; r < 4; r++)
        #pragma unroll
        for (int o = 1; o < 16; o <<= 1) mx[r] = fmaxf(mx[r], __shfl_xor(mx[r], o));
    float sm[4] = {0.f, 0.f, 0.f, 0.f};
    #pragma unroll
    for (int t = 0; t < 32; t++)
        #pragma unroll
        for (int r = 0; r < 4; r++) {
            float e = __expf(acc[t][r] - mx[r]);
            acc[t][r] = e;
            sm[r] += e;
        }
    #pragma unroll
    for (int r = 0; r < 4; r++)
        #pragma unroll
        for (int o = 1; o < 16; o <<= 1) sm[r] += __shfl_xor(sm[r], o);
    float inv[4];
    #pragma unroll
    for (int r = 0; r < 4; r++) inv[r] = 1.f / sm[r];
    #pragma unroll
    for (int t = 0; t < 32; t++)
        #pragma unroll
        for (int r = 0; r < 4; r++)
            pt[w][(quad * 4 + r) * 512 + t * 16 + l16] = (__bf16)(acc[t][r] * inv[r]);
    __syncthreads();
    f32x4 oacc[4] = {};
    for (int kk = 0; kk < 512; kk += 32) {
        bf16x8 pf = *(const bf16x8*)&pt[w][l16 * 512 + kk + quad * 8];
        #pragma unroll
        for (int j = 0; j < 4; j++) {
            const __bf16* vrow = vT + ((long)bh * 64 + j * 16 + l16) * 512 + kk + quad * 8;
            bf16x8 vf = *(const bf16x8*)(vrow);
            oacc[j] = __builtin_amdgcn_mfma_f32_16x16x32_bf16(pf, vf, oacc[j], 0, 0, 0);
        }
    }
    #pragma unroll
    for (int j = 0; j < 4; j++)
        #pragma unroll
        for (int r = 0; r < 4; r++) {
            int m = qr0 + quad * 4 + r, d = j * 16 + l16;
            attno[((long)(b * 512 + m)) * 256 + h * 64 + d] = (__bf16)oacc[j][r];
        }
}

// ---------------------------------------------------------------- launch
extern "C" void kernel_launch(void* const* d_in, const int* in_sizes, int n_in,
                              void* d_out, int out_size, void* d_ws, size_t ws_size,
                              hipStream_t stream) {
    const long MB = 1024 * 1024;

    const int* ei   = (const int*)d_in[31];
    const int* drop = (const int*)d_in[33];
    const int* esrc = ei;
    const int* edst = ei + NEG;

    // ---- workspace layout (59 MB, no overlays; validated in-bounds in R5/R6) ----
    char* ws = (char*)d_ws;
    float*  xb    = (float*)(ws + 0);                          // 8 MB
    __bf16* arena = (__bf16*)(ws + 8 * MB);                    // 7.1 MB
    unsigned int* maskw = (unsigned int*)(ws + 15 * MB + 512 * 1024); // 0.5 MB
    float*  agg1  = (float*)(ws + 16 * MB);                    // 64 KB
    float*  agg2  = (float*)(ws + 17 * MB);                    // 4 MB
    float*  h1f   = (float*)(ws + 21 * MB);                    // 4 MB
    __bf16* z2b   = (__bf16*)(ws + 25 * MB);                   // 2 MB
    __bf16* t1b   = (__bf16*)(ws + 27 * MB);                   // 4 MB
    __bf16* hnb   = (__bf16*)(ws + 31 * MB);                   // 4 MB
    __bf16* qkb   = (__bf16*)(ws + 35 * MB);                   // 8 MB
    __bf16* vT    = (__bf16*)(ws + 43 * MB);                   // 4 MB
    __bf16* attno = (__bf16*)(ws + 47 * MB);                   // 4 MB
    __bf16* ff1b  = (__bf16*)(ws + 51 * MB);                   // 8 MB

    SrcPtrs sp;
    __bf16* ap[N_SRC];
    long off = 0;
    for (int i = 0; i < N_SRC; i++) {
        sp.p[i] = d_in[i];
        ap[i] = arena + off;
        off += (asz_at(i) + 15) & ~15L;
    }
    convert_arena<<<(int)((off + 255) / 256), 256, 0, stream>>>(sp, arena, off);

    const __bf16 *xA = ap[0], *eaA = ap[1], *eps1A = ap[2], *ew1A = ap[3], *eb1A = ap[4],
                 *n1w1A = ap[5], *n1b1A = ap[6], *n1w2A = ap[7], *n1b2A = ap[8],
                 *eps2A = ap[9], *ew2A = ap[10], *eb2A = ap[11],
                 *n2w1A = ap[12], *n2b1A = ap[13], *n2w2A = ap[14], *n2b2A = ap[15],
                 *posA = ap[16], *ipwA = ap[17], *ipbA = ap[18], *opwA = ap[19], *opbA = ap[20],
                 *ln1wA = ap[21], *ln1bA = ap[22], *ln2wA = ap[23], *ln2bA = ap[24],
                 *f1wA = ap[25], *f1bA = ap[26], *f2wA = ap[27], *f2bA = ap[28],
                 *fnwA = ap[29], *fnbA = ap[30];

    hipMemsetAsync(agg1, 0, (size_t)NND * 2 * 4, stream);
    hipMemsetAsync(agg2, 0, (size_t)NND * 128 * 4, stream);
    hipMemsetAsync(maskw, 0, (size_t)512 * 1024, stream);

    gine1_edge<<<NEG / 256, 256, 0, stream>>>(xA, eaA, esrc, edst, ew1A, eb1A, agg1);
    gine1_node<<<NND / 2, 256, 0, stream>>>(xA, agg1, eps1A, n1w1A, n1b1A, n1w2A, n1b2A, h1f);
    gine2_edge<<<(NEG * 128) / 256, 256, 0, stream>>>(h1f, eaA, esrc, edst, ew2A, eb2A, agg2);
    make_z2<<<(NND * 128) / 256, 256, 0, stream>>>(h1f, agg2, eps2A, z2b);

    gemm_bt<<<dim3(NND / 128, 4), 256, 0, stream>>>(z2b, n2w1A, n2b1A, t1b, nullptr, nullptr, nullptr, nullptr,
                                                    128, 256, 1, 0);
    gemm_bt<<<dim3(NND / 128, 4), 256, 0, stream>>>(t1b, n2w2A, n2b2A, nullptr, xb, nullptr, posA, nullptr,
                                                    256, 256, 0, 0);

    drop_mask<<<NEG / 256, 256, 0, stream>>>(esrc, edst, drop, maskw);

    for (int l = 0; l < NLY; l++) {
        ln_k<<<NND / 4, 256, 0, stream>>>(xb, ln1wA + l * 256, ln1bA + l * 256, hnb);
        gemm_bt<<<dim3(NND / 128, 12), 256, 0, stream>>>(hnb, ipwA + (long)l * 768 * 256, ipbA + l * 768,
                                                         qkb, nullptr, nullptr, nullptr, vT,
                                                         256, 512, 0, 1);
        attn_fused<<<dim3(8, NHD, BSZ), 256, 0, stream>>>(qkb, vT, maskw, attno);
        gemm_bt<<<dim3(NND / 128, 4), 256, 0, stream>>>(attno, opwA + (long)l * 256 * 256, opbA + l * 256,
                                                        nullptr, xb, xb, nullptr, nullptr,
                                                        256, 256, 0, 0);
        ln_k<<<NND / 4, 256, 0, stream>>>(xb, ln2wA + l * 256, ln2bA + l * 256, hnb);
        gemm_bt<<<dim3(NND / 128, 8), 256, 0, stream>>>(hnb, f1wA + (long)l * 512 * 256, f1bA + l * 512,
                                                        ff1b, nullptr, nullptr, nullptr, nullptr,
                                                        256, 512, 2, 0);
        gemm_bt<<<dim3(NND / 128, 4), 256, 0, stream>>>(ff1b, f2wA + (long)l * 256 * 512, f2bA + l * 256,
                                                        nullptr, xb, xb, nullptr, nullptr,
                                                        512, 256, 0, 0);
    }
    ln_out<<<NND / 4, 256, 0, stream>>>(xb, fnwA, fnbA, (float*)d_out);
}